// Round 7
// baseline (39687.265 us; speedup 1.0000x reference)
//
#include <hip/hip_runtime.h>
#include <math.h>

// Problem constants
#define B 256
#define Hh 512
#define S 200
#define T 200
#define VOC 512
#define G3 1536
#define PAD 36

// fp64 helpers: inner-product math in double, tensor boundaries quantized fp32.
struct d4 { double x, y, z, w; };
__device__ __forceinline__ d4 tod4(const float4 a) {
    d4 r; r.x = a.x; r.y = a.y; r.z = a.z; r.w = a.w; return r;
}
__device__ __forceinline__ double dotd(const d4& a, const d4& b) {
    return a.x * b.x + a.y * b.y + a.z * b.z + a.w * b.w;
}
__device__ __forceinline__ double sigd(double x) { return 1.0 / (1.0 + exp(-x)); }

// ---------------------------------------------------------------------------
// Table-precompute GEMM (R0 proven, one-time).
// ---------------------------------------------------------------------------
__global__ __launch_bounds__(256) void gemm_at(
    const float* __restrict__ A,
    const float* __restrict__ W, int ldw, int woff,
    const float* __restrict__ bias,
    float* __restrict__ C, int ldc)
{
    __shared__ float As[32][PAD];
    __shared__ float Ws[32][PAD];
    const int tid = threadIdx.x;
    const int tx = tid & 15, ty = tid >> 4;
    const int j0 = blockIdx.x * 32, m0 = blockIdx.y * 32;
    const int lr = tid >> 3, lc = (tid & 7) * 4;

    double acc00 = 0.0, acc01 = 0.0, acc10 = 0.0, acc11 = 0.0;

    for (int k0 = 0; k0 < 512; k0 += 32) {
        float4 av = *(const float4*)(A + (size_t)(m0 + lr) * 512 + k0 + lc);
        float4 wv = *(const float4*)(W + (size_t)(j0 + lr) * ldw + woff + k0 + lc);
        __syncthreads();
        *(float4*)&As[lr][lc] = av;
        *(float4*)&Ws[lr][lc] = wv;
        __syncthreads();
#pragma unroll
        for (int kk = 0; kk < 32; kk += 4) {
            d4 a0 = tod4(*(const float4*)&As[ty][kk]);
            d4 a1 = tod4(*(const float4*)&As[ty + 16][kk]);
            d4 b0 = tod4(*(const float4*)&Ws[tx][kk]);
            d4 b1 = tod4(*(const float4*)&Ws[tx + 16][kk]);
            acc00 += dotd(a0, b0);
            acc01 += dotd(a0, b1);
            acc10 += dotd(a1, b0);
            acc11 += dotd(a1, b1);
        }
    }
    const int ms[2] = { m0 + ty, m0 + ty + 16 };
    const int js[2] = { j0 + tx, j0 + tx + 16 };
    double accs[2][2] = { { acc00, acc01 }, { acc10, acc11 } };
#pragma unroll
    for (int mi = 0; mi < 2; ++mi)
#pragma unroll
        for (int ji = 0; ji < 2; ++ji) {
            int m = ms[mi], j = js[ji];
            C[(size_t)m * ldc + j] = (float)(accs[mi][ji] + (double)bias[j]);
        }
}

// ---------------------------------------------------------------------------
// Encoder GRU step v2: 256 thr, 16j x 16b tile, grid (32,16) = 512 blocks
// (2 blocks/CU overlap), k-chunk 64 with register prefetch (stage of chunk
// k+1 issued under compute of chunk k). Per-output fp64 k-ascending sums and
// epilogue BITWISE IDENTICAL to R0's enc_step.
// ---------------------------------------------------------------------------
__global__ __launch_bounds__(256) void enc_step2(
    const float* __restrict__ h_in, float* __restrict__ h_out,
    const float* __restrict__ gi_tab, const int* __restrict__ iseq,
    const int* __restrict__ ilen, const float* __restrict__ Whh,
    const float* __restrict__ bhh, int s, float* __restrict__ enc_out)
{
    __shared__ float Hs[16][68];
    __shared__ float Ws[48][68];
    const int tid = threadIdx.x;
    const int j_l = tid & 15, b_l = tid >> 4;
    const int j0 = blockIdx.x * 16, b0 = blockIdx.y * 16;
    const int j = j0 + j_l, b = b0 + b_l;

    int ml = 0;
    for (int i = 0; i < 16; ++i) ml = max(ml, ilen[b0 + i]);
    if (s >= ml) {   // block-uniform early-out (R0 semantics per b)
        h_out[(size_t)b * 512 + j] = h_in[(size_t)b * 512 + j];
        enc_out[((size_t)s * B + b) * 512 + j] = 0.f;
        return;
    }

    // stage rows: 0-15 = h_in[b0+row], 16-63 = Whh gate rows (3x16 for j0-tile)
    const int srow = (tid >> 4) & 63;   // helper vars for lambda-free addressing
    float4 pre[4];
#pragma unroll
    for (int i = 0; i < 4; ++i) {
        int x4 = i * 256 + tid, row = x4 >> 4, c4 = (x4 & 15) * 4;
        const float* p = (row < 16)
            ? (h_in + (size_t)(b0 + row) * 512 + c4)
            : (Whh + (size_t)(((row - 16) >> 4) * 512 + j0 + ((row - 16) & 15)) * 512 + c4);
        pre[i] = *(const float4*)p;
    }
    (void)srow;

    double ar = 0.0, az = 0.0, an = 0.0;
    for (int kt = 0; kt < 512; kt += 64) {
        __syncthreads();
#pragma unroll
        for (int i = 0; i < 4; ++i) {
            int x4 = i * 256 + tid, row = x4 >> 4, c4 = (x4 & 15) * 4;
            if (row < 16) *(float4*)&Hs[row][c4] = pre[i];
            else          *(float4*)&Ws[row - 16][c4] = pre[i];
        }
        __syncthreads();
        if (kt + 64 < 512) {
#pragma unroll
            for (int i = 0; i < 4; ++i) {
                int x4 = i * 256 + tid, row = x4 >> 4, c4 = (x4 & 15) * 4;
                const float* p = (row < 16)
                    ? (h_in + (size_t)(b0 + row) * 512 + kt + 64 + c4)
                    : (Whh + (size_t)(((row - 16) >> 4) * 512 + j0 + ((row - 16) & 15)) * 512 + kt + 64 + c4);
                pre[i] = *(const float4*)p;
            }
        }
#pragma unroll
        for (int kk = 0; kk < 64; kk += 4) {
            d4 hv = tod4(*(const float4*)&Hs[b_l][kk]);
            ar += dotd(hv, tod4(*(const float4*)&Ws[j_l][kk]));
            az += dotd(hv, tod4(*(const float4*)&Ws[16 + j_l][kk]));
            an += dotd(hv, tod4(*(const float4*)&Ws[32 + j_l][kk]));
        }
    }

    float hold = h_in[(size_t)b * 512 + j];
    float hnew = hold;
    if (s < ilen[b]) {
        int tok = iseq[s * B + b];
        const float* gi = gi_tab + (size_t)tok * G3;
        double r = sigd((double)gi[j] + ar + (double)bhh[j]);
        double z = sigd((double)gi[512 + j] + az + (double)bhh[512 + j]);
        double n = tanh((double)gi[1024 + j] + r * (an + (double)bhh[1024 + j]));
        hnew = (float)((1.0 - z) * n + z * (double)hold);
        enc_out[((size_t)s * B + b) * 512 + j] = hnew;
    } else {
        enc_out[((size_t)s * B + b) * 512 + j] = 0.f;
    }
    h_out[(size_t)b * 512 + j] = hnew;
}

// ---------------------------------------------------------------------------
// proj v2: 256 thr, 16R x 16m tile, grid (64,16) = 1024 blocks (4 blocks/CU),
// k-chunk 64 + register prefetch. Stacked rows [att_W | out_W]. Per-output
// fp64 sums and epilogue BITWISE IDENTICAL to R0's proj.
// ---------------------------------------------------------------------------
__global__ __launch_bounds__(256) void proj2(
    const float* __restrict__ h,
    const float* __restrict__ att_W, const float* __restrict__ att_b,
    const float* __restrict__ out_W, const float* __restrict__ out_b,
    float* __restrict__ ah, float* __restrict__ logits, int t)
{
    __shared__ float As[16][68];
    __shared__ float Ws[16][68];
    const int tid = threadIdx.x;
    const int tx = tid & 15, ty = tid >> 4;
    const int Rb0 = blockIdx.x * 16, m0 = blockIdx.y * 16;
    const bool is_att = (Rb0 < 512);
    if (is_att && t >= T) return;   // block-uniform

    float4 pre[2];
#pragma unroll
    for (int i = 0; i < 2; ++i) {
        int x4 = i * 256 + tid, row = x4 >> 4, c4 = (x4 & 15) * 4;
        const float* p;
        if (row < 16) p = h + (size_t)(m0 + row) * 512 + c4;
        else {
            int R = Rb0 + row - 16;
            p = is_att ? (att_W + (size_t)R * 512 + c4)
                       : (out_W + (size_t)(R - 512) * 512 + c4);
        }
        pre[i] = *(const float4*)p;
    }

    double a0 = 0.0;
    for (int kt = 0; kt < 512; kt += 64) {
        __syncthreads();
#pragma unroll
        for (int i = 0; i < 2; ++i) {
            int x4 = i * 256 + tid, row = x4 >> 4, c4 = (x4 & 15) * 4;
            if (row < 16) *(float4*)&As[row][c4] = pre[i];
            else          *(float4*)&Ws[row - 16][c4] = pre[i];
        }
        __syncthreads();
        if (kt + 64 < 512) {
#pragma unroll
            for (int i = 0; i < 2; ++i) {
                int x4 = i * 256 + tid, row = x4 >> 4, c4 = (x4 & 15) * 4;
                const float* p;
                if (row < 16) p = h + (size_t)(m0 + row) * 512 + kt + 64 + c4;
                else {
                    int R = Rb0 + row - 16;
                    p = is_att ? (att_W + (size_t)R * 512 + kt + 64 + c4)
                               : (out_W + (size_t)(R - 512) * 512 + kt + 64 + c4);
                }
                pre[i] = *(const float4*)p;
            }
        }
#pragma unroll
        for (int kk = 0; kk < 64; kk += 4) {
            a0 += dotd(tod4(*(const float4*)&As[ty][kk]),
                       tod4(*(const float4*)&Ws[tx][kk]));
        }
    }

    const int m = m0 + ty;
    const int R = Rb0 + tx;
    if (is_att) {
        double v0 = a0 + (double)att_b[R]; if (v0 < 0.0) v0 = 0.0;
        ah[(size_t)m * 512 + R] = (float)v0;
    } else {
        logits[(size_t)m * 512 + (R - 512)] = (float)(a0 + (double)out_b[R - 512]);
    }
}

// ---------------------------------------------------------------------------
// F2 (R0 proven, verbatim): attention + x | softmax/argmax/nll.
// ---------------------------------------------------------------------------
__global__ __launch_bounds__(256) void attn_x_softmax(
    const float* __restrict__ enc_out, const float* __restrict__ ah,
    const float* __restrict__ mlp_W, const float* __restrict__ mlp_tab,
    const int* __restrict__ input_len, const int* __restrict__ target_seq,
    const float* __restrict__ logits, int t,
    float* __restrict__ xbuf, float* __restrict__ nll,
    float* __restrict__ inference)
{
    const int bid = blockIdx.x, tid = threadIdx.x;

    if (bid < B) {
        if (t >= T) return;
        __shared__ float scx[4][512];
        __shared__ double sml[8];
        __shared__ float ctxl[512];
        const int b = bid;
        const int wave = tid >> 6, lane = tid & 63;
        const int len = input_len[b];
        const float* ahb = ah + (size_t)b * 512;
        d4 aa1 = tod4(*(const float4*)(ahb + lane * 4));
        d4 aa2 = tod4(*(const float4*)(ahb + 256 + lane * 4));
        double m = -INFINITY, l = 0.0;
        d4 c1 = {0,0,0,0}, c2 = {0,0,0,0};
        for (int s = wave; s < len; s += 4) {
            const float* row = enc_out + ((size_t)s * B + b) * 512;
            d4 e1 = tod4(*(const float4*)(row + lane * 4));
            d4 e2 = tod4(*(const float4*)(row + 256 + lane * 4));
            double p = dotd(e1, aa1) + dotd(e2, aa2);
#pragma unroll
            for (int off = 32; off >= 1; off >>= 1) p += __shfl_xor(p, off, 64);
            double mn = fmax(m, p);
            double sc = (m == mn) ? 1.0 : exp(m - mn);   // exp(0)==1 exactly
            double w = exp(p - mn);
            l = l * sc + w;
            c1.x = c1.x * sc + w * e1.x; c1.y = c1.y * sc + w * e1.y;
            c1.z = c1.z * sc + w * e1.z; c1.w = c1.w * sc + w * e1.w;
            c2.x = c2.x * sc + w * e2.x; c2.y = c2.y * sc + w * e2.y;
            c2.z = c2.z * sc + w * e2.z; c2.w = c2.w * sc + w * e2.w;
            m = mn;
        }
        if (lane == 0) { sml[wave] = m; sml[4 + wave] = l; }
        *(float4*)&scx[wave][lane * 4] =
            make_float4((float)c1.x, (float)c1.y, (float)c1.z, (float)c1.w);
        *(float4*)&scx[wave][256 + lane * 4] =
            make_float4((float)c2.x, (float)c2.y, (float)c2.z, (float)c2.w);
        __syncthreads();
        double M = fmax(fmax(sml[0], sml[1]), fmax(sml[2], sml[3]));
        if (len < S) M = fmax(M, 0.0);   // zero rows participate in softmax
        double w0 = exp(sml[0] - M), w1x = exp(sml[1] - M);
        double w2x = exp(sml[2] - M), w3 = exp(sml[3] - M);
        double L = sml[4] * w0 + sml[5] * w1x + sml[6] * w2x + sml[7] * w3
                 + (double)(S - len) * exp(0.0 - M);   // analytic zero tail
        for (int jj = tid; jj < 512; jj += 256) {
            double v = (double)scx[0][jj] * w0 + (double)scx[1][jj] * w1x
                     + (double)scx[2][jj] * w2x + (double)scx[3][jj] * w3;
            ctxl[jj] = (float)(v / L);   // fp32 quantization boundary (as ref)
        }
        __syncthreads();

        // x = tanh(mlp_tab[tok] + ctx @ mlpW2.T): quad-per-row (R0 proven)
        const int tok = (t == 0) ? 1 : target_seq[(t - 1) * B + b];
        const int q = tid & 3;
        const int rbase = tid >> 2;                 // 0..63
#pragma unroll
        for (int pass = 0; pass < 8; ++pass) {
            const int jr = pass * 64 + rbase;
            const float* wr = mlp_W + (size_t)jr * 1024 + 512;
            double a = 0.0;
            for (int k = q * 4; k < 512; k += 16) {
                a += dotd(tod4(*(const float4*)&ctxl[k]),
                          tod4(*(const float4*)(wr + k)));
            }
            a += __shfl_xor(a, 1, 64);
            a += __shfl_xor(a, 2, 64);
            if (q == 0)
                xbuf[(size_t)b * 512 + jr] =
                    (float)tanh((double)mlp_tab[(size_t)tok * 512 + jr] + a);
        }
    } else {
        if (t < 1) return;
        __shared__ float red_f[256];
        __shared__ double red_d[256];
        __shared__ int red_i[256];
        const int sb = bid - B;
        const float* lg = logits + (size_t)sb * 512;
        const float l0 = lg[tid], l1 = lg[256 + tid];
        red_f[tid] = fmaxf(l0, l1);
        __syncthreads();
        for (int off = 128; off > 0; off >>= 1) {
            if (tid < off) red_f[tid] = fmaxf(red_f[tid], red_f[tid + off]);
            __syncthreads();
        }
        const double mx = (double)red_f[0];
        __syncthreads();
        const double e0 = exp((double)l0 - mx), e1 = exp((double)l1 - mx);
        red_d[tid] = e0 + e1;
        __syncthreads();
        for (int off = 128; off > 0; off >>= 1) {
            if (tid < off) red_d[tid] += red_d[tid + off];
            __syncthreads();
        }
        const double Z = red_d[0];
        __syncthreads();
        const float p0 = (float)(e0 / Z), p1 = (float)(e1 / Z);
        float v; int idx;
        if (p0 >= p1) { v = p0; idx = tid; } else { v = p1; idx = 256 + tid; }
        red_f[tid] = v; red_i[tid] = idx;
        __syncthreads();
        for (int off = 128; off > 0; off >>= 1) {
            if (tid < off) {
                float ov = red_f[tid + off]; int oi = red_i[tid + off];
                if (ov > red_f[tid] || (ov == red_f[tid] && oi < red_i[tid])) {
                    red_f[tid] = ov; red_i[tid] = oi;
                }
            }
            __syncthreads();
        }
        if (tid == 0) {
            int tg = target_seq[(t - 1) * B + sb];
            float pt = (float)(exp((double)lg[tg] - mx) / Z);
            pt = fmaxf(pt, 1e-10f);
            nll[(t - 1) * B + sb] = (float)(-log((double)pt));
            inference[(t - 1) * B + sb] = (float)red_i[0];
        }
    }
}

// ---------------------------------------------------------------------------
// Decoder GRU v2: 256 thr, 16b x 16j tile, grid (32,16), k-chunk 64 (was 32)
// + register prefetch. Per-output fp64 k-ascending sums and epilogue BITWISE
// IDENTICAL to R0's dec_gru (chunk size does not change summation order).
// ---------------------------------------------------------------------------
__global__ __launch_bounds__(256) void dec_gru2(
    const float* __restrict__ x, const float* __restrict__ h_in,
    const float* __restrict__ Wih, const float* __restrict__ Whh,
    const float* __restrict__ bih, const float* __restrict__ bhh,
    float* __restrict__ h_out)
{
    __shared__ float Xs[16][68];
    __shared__ float Hs2[16][68];
    __shared__ float Wi[48][68];
    __shared__ float Wh[48][68];
    const int tid = threadIdx.x;
    const int j_l = tid & 15, b_l = tid >> 4;
    const int j0 = blockIdx.x * 16, b0 = blockIdx.y * 16;
    const int j = j0 + j_l, b = b0 + b_l;

    // stage rows: 0-15 Xs, 16-31 Hs2, 32-79 Wi, 80-127 Wh (each 64 floats)
    float4 pre[8];
#pragma unroll
    for (int i = 0; i < 8; ++i) {
        int x4 = i * 256 + tid, row = x4 >> 4, c4 = (x4 & 15) * 4;
        const float* p;
        if (row < 16)      p = x + (size_t)(b0 + row) * 512 + c4;
        else if (row < 32) p = h_in + (size_t)(b0 + row - 16) * 512 + c4;
        else if (row < 80) {
            int r = row - 32;
            p = Wih + (size_t)((r >> 4) * 512 + j0 + (r & 15)) * 512 + c4;
        } else {
            int r = row - 80;
            p = Whh + (size_t)((r >> 4) * 512 + j0 + (r & 15)) * 512 + c4;
        }
        pre[i] = *(const float4*)p;
    }

    double air = 0, aiz = 0, ain = 0, ahr = 0, ahz = 0, ahn = 0;
    for (int kt = 0; kt < 512; kt += 64) {
        __syncthreads();
#pragma unroll
        for (int i = 0; i < 8; ++i) {
            int x4 = i * 256 + tid, row = x4 >> 4, c4 = (x4 & 15) * 4;
            if (row < 16)      *(float4*)&Xs[row][c4] = pre[i];
            else if (row < 32) *(float4*)&Hs2[row - 16][c4] = pre[i];
            else if (row < 80) *(float4*)&Wi[row - 32][c4] = pre[i];
            else               *(float4*)&Wh[row - 80][c4] = pre[i];
        }
        __syncthreads();
        if (kt + 64 < 512) {
#pragma unroll
            for (int i = 0; i < 8; ++i) {
                int x4 = i * 256 + tid, row = x4 >> 4, c4 = (x4 & 15) * 4;
                const float* p;
                if (row < 16)      p = x + (size_t)(b0 + row) * 512 + kt + 64 + c4;
                else if (row < 32) p = h_in + (size_t)(b0 + row - 16) * 512 + kt + 64 + c4;
                else if (row < 80) {
                    int r = row - 32;
                    p = Wih + (size_t)((r >> 4) * 512 + j0 + (r & 15)) * 512 + kt + 64 + c4;
                } else {
                    int r = row - 80;
                    p = Whh + (size_t)((r >> 4) * 512 + j0 + (r & 15)) * 512 + kt + 64 + c4;
                }
                pre[i] = *(const float4*)p;
            }
        }
#pragma unroll
        for (int kk = 0; kk < 64; kk += 4) {
            d4 xv = tod4(*(const float4*)&Xs[b_l][kk]);
            d4 hv = tod4(*(const float4*)&Hs2[b_l][kk]);
            air += dotd(xv, tod4(*(const float4*)&Wi[j_l][kk]));
            aiz += dotd(xv, tod4(*(const float4*)&Wi[16 + j_l][kk]));
            ain += dotd(xv, tod4(*(const float4*)&Wi[32 + j_l][kk]));
            ahr += dotd(hv, tod4(*(const float4*)&Wh[j_l][kk]));
            ahz += dotd(hv, tod4(*(const float4*)&Wh[16 + j_l][kk]));
            ahn += dotd(hv, tod4(*(const float4*)&Wh[32 + j_l][kk]));
        }
    }

    double r = sigd(air + (double)bih[j] + ahr + (double)bhh[j]);
    double z = sigd(aiz + (double)bih[512 + j] + ahz + (double)bhh[512 + j]);
    double n = tanh(ain + (double)bih[1024 + j] + r * (ahn + (double)bhh[1024 + j]));
    float hold = h_in[(size_t)b * 512 + j];
    h_out[(size_t)b * 512 + j] = (float)((1.0 - z) * n + z * (double)hold);
}

// ---------------------------------------------------------------------------
// Final reduction (R0 proven).
// ---------------------------------------------------------------------------
__global__ __launch_bounds__(256) void finalize_k(
    const float* __restrict__ nll, const float* __restrict__ inference,
    const int* __restrict__ target, float* __restrict__ out3)
{
    const int tid = threadIdx.x;
    int wrong = 0;
    double match = 0.0;
    const int b = tid;
    for (int t = 0; t < T; ++t) {
        float inf = inference[t * B + b];
        float tg = (float)target[t * B + b];
        bool ok = (inf == tg);
        match += ok ? 1.0 : 0.0;
        wrong |= !ok;
    }
    double lsum = 0.0;
    for (int i = tid; i < T * B; i += 256) lsum += (double)nll[i];

    __shared__ double sl[256], sm_[256], sa[256];
    sl[tid] = lsum; sm_[tid] = match; sa[tid] = wrong ? 0.0 : 1.0;
    __syncthreads();
    for (int off = 128; off > 0; off >>= 1) {
        if (tid < off) {
            sl[tid] += sl[tid + off];
            sm_[tid] += sm_[tid + off];
            sa[tid] += sa[tid + off];
        }
        __syncthreads();
    }
    if (tid == 0) {
        out3[0] = (float)(sl[0] / (double)(T * B));
        out3[1] = (float)(sa[0] / (double)B);
        out3[2] = (float)(sm_[0] / (double)(T * B));
    }
}

// ---------------------------------------------------------------------------
extern "C" void kernel_launch(void* const* d_in, const int* in_sizes, int n_in,
                              void* d_out, int out_size, void* d_ws, size_t ws_size,
                              hipStream_t stream)
{
    const int*   input_seq  = (const int*)d_in[0];
    const int*   input_len  = (const int*)d_in[1];
    const int*   target_seq = (const int*)d_in[2];
    const float* enc_embed  = (const float*)d_in[3];
    const float* enc_Wih    = (const float*)d_in[4];
    const float* enc_Whh    = (const float*)d_in[5];
    const float* enc_bih    = (const float*)d_in[6];
    const float* enc_bhh    = (const float*)d_in[7];
    const float* att_W      = (const float*)d_in[8];
    const float* att_b      = (const float*)d_in[9];
    const float* dec_embed  = (const float*)d_in[10];
    const float* dec_Wih    = (const float*)d_in[11];
    const float* dec_Whh    = (const float*)d_in[12];
    const float* dec_bih    = (const float*)d_in[13];
    const float* dec_bhh    = (const float*)d_in[14];
    const float* mlp_W      = (const float*)d_in[15];
    const float* mlp_b      = (const float*)d_in[16];
    const float* out_W      = (const float*)d_in[17];
    const float* out_b      = (const float*)d_in[18];

    float* out = (float*)d_out;   // [inference (T*B) | loss | acc | all_acc]

    float* gi_tab  = (float*)d_ws;                   // (V, 3H)
    float* mlp_tab = gi_tab + (size_t)VOC * G3;      // (V, H)
    float* h0      = mlp_tab + (size_t)VOC * Hh;     // (B, H)
    float* h1      = h0 + (size_t)B * Hh;
    float* ahb     = h1 + (size_t)B * Hh;
    float* xb      = ahb + (size_t)B * Hh;
    float* lgb     = xb + (size_t)B * Hh;
    float* nllb    = lgb + (size_t)B * Hh;           // (T, B)
    float* enc_out = nllb + (size_t)T * B;           // (S, B, H) ~100 MB

    hipMemsetAsync(h0, 0, (size_t)B * Hh * sizeof(float), stream);

    // Precompute tables:
    gemm_at<<<dim3(48, 16), 256, 0, stream>>>(
        enc_embed, enc_Wih, 512, 0, enc_bih, gi_tab, G3);
    gemm_at<<<dim3(16, 16), 256, 0, stream>>>(
        dec_embed, mlp_W, 1024, 0, mlp_b, mlp_tab, Hh);

    // Encoder scan (final h lands in h0: s=199 odd writes h0)
    for (int s = 0; s < S; ++s) {
        const float* hc = (s & 1) ? h1 : h0;
        float* hx = (s & 1) ? h0 : h1;
        enc_step2<<<dim3(32, 16), 256, 0, stream>>>(
            hc, hx, gi_tab, input_seq, input_len, enc_Whh, enc_bhh, s, enc_out);
    }

    // Decoder scan: t = 0..T; at t==T only logits(h_T) + softmax(T-1) remain.
    for (int t = 0; t <= T; ++t) {
        const float* hc = (t & 1) ? h1 : h0;
        float* hx = (t & 1) ? h0 : h1;
        proj2<<<dim3(64, 16), 256, 0, stream>>>(
            hc, att_W, att_b, out_W, out_b, ahb, lgb, t);
        attn_x_softmax<<<dim3(2 * B), 256, 0, stream>>>(
            enc_out, ahb, mlp_W, mlp_tab, input_len, target_seq,
            lgb, t, xb, nllb, out);
        if (t < T) {
            dec_gru2<<<dim3(32, 16), 256, 0, stream>>>(
                xb, hc, dec_Wih, dec_Whh, dec_bih, dec_bhh, hx);
        }
    }

    finalize_k<<<dim3(1), 256, 0, stream>>>(nllb, out, target_seq, out + (size_t)T * B);
}